// Round 6
// baseline (368.523 us; speedup 1.0000x reference)
//
#include <hip/hip_runtime.h>
#include <math.h>

// ---------------------------------------------------------------------------
// ShrdMHAttention: z = (sum_h softmax_causal(rope(xQ) rope(xK)^T) (xV) O_h) * scale
// SEQ=2048, D_MODEL=2048, NH=16, DQK=DV=128.
//
// Precision: q/k proj and QK^T use 2-term fp16 split (hh+hl+lh); v/PV/out are
// single fp16.  Measured absmax 0.031 vs 0.102 threshold (R1-R5).
//
// R6: flash rebuilt as BM=128 split-K: wave owns 32 q-rows (each K-fragment
// LDS read feeds 3 MFMAs instead of 1.5 -> LDS traffic halves), K-range of
// each (h,qtile) split across 2 blocks (512 blocks, 2/CU, complementary
// pairing = uniform 17 kb/CU).  Partial (m,l,O_fp32) merged by k_fmerge.
// ---------------------------------------------------------------------------

typedef _Float16 half_t;
typedef __attribute__((ext_vector_type(8))) _Float16 half8;
typedef __attribute__((ext_vector_type(4))) float f32x4;

#define SEQ   2048
#define DM    2048
#define NHEAD 16

__device__ __forceinline__ f32x4 mfma16(half8 a, half8 b, f32x4 c) {
  return __builtin_amdgcn_mfma_f32_16x16x32_f16(a, b, c, 0, 0, 0);
}

__device__ __forceinline__ void gll16(const half_t* g, half_t* l) {
  __builtin_amdgcn_global_load_lds(
      (const __attribute__((address_space(1))) unsigned int*)g,
      (__attribute__((address_space(3))) unsigned int*)l, 16, 0, 0);
}

// DPP lane-permute within contiguous 16-lane rows (VALU, no LDS pipe).
template <int CTRL>
__device__ __forceinline__ float dppf(float v) {
  int r = __builtin_amdgcn_mov_dpp(__builtin_bit_cast(int, v), CTRL, 0xF, 0xF,
                                   true);
  return __builtin_bit_cast(float, r);
}
__device__ __forceinline__ float red16_max(float v) {
  v = fmaxf(v, dppf<0xB1>(v));   // quad_perm [1,0,3,2]
  v = fmaxf(v, dppf<0x4E>(v));   // quad_perm [2,3,0,1]
  v = fmaxf(v, dppf<0x141>(v));  // row_half_mirror
  v = fmaxf(v, dppf<0x140>(v));  // row_mirror
  return v;
}
__device__ __forceinline__ float red16_sum(float v) {
  v += dppf<0xB1>(v);
  v += dppf<0x4E>(v);
  v += dppf<0x141>(v);
  v += dppf<0x140>(v);
  return v;
}

// ---------------------------------------------------------------------------
// k_pre: one launch for x hi/lo split, q/k/v/o transposes, trig table.
__device__ __forceinline__ void tpose32(const float* __restrict__ in,
                                        half_t* __restrict__ hi,
                                        half_t* __restrict__ lo, int R, int C,
                                        int r0, int c0, float (*tile)[33],
                                        int tid) {
  int tx = tid & 31, ty = tid >> 5;
#pragma unroll
  for (int i = 0; i < 32; i += 8)
    tile[ty + i][tx] = in[(size_t)(r0 + ty + i) * C + c0 + tx];
  __syncthreads();
#pragma unroll
  for (int i = 0; i < 32; i += 8) {
    float v = tile[tx][ty + i];
    half_t h = (half_t)v;
    size_t oidx = (size_t)(c0 + ty + i) * R + r0 + tx;
    hi[oidx] = h;
    if (lo) lo[oidx] = (half_t)(v - (float)h);
  }
}

__global__ __launch_bounds__(256)
void k_pre(const float* __restrict__ x, const float* __restrict__ q,
           const float* __restrict__ k, const float* __restrict__ v,
           const float* __restrict__ o, const float* __restrict__ thetap,
           half_t* __restrict__ Xh, half_t* __restrict__ Xl,
           half_t* __restrict__ WTh, half_t* __restrict__ WTl,
           half_t* __restrict__ VhT, half_t* __restrict__ OT,
           float2* __restrict__ trig) {
  __shared__ float tile[32][33];
  int b = blockIdx.x, tid = threadIdx.x;
  if (b < 4096) {
    int i = b * 256 + tid;
    float4 vv = ((const float4*)x)[i];
    union { half_t h[4]; uint2 u; } H, L;
    H.h[0] = (half_t)vv.x; H.h[1] = (half_t)vv.y;
    H.h[2] = (half_t)vv.z; H.h[3] = (half_t)vv.w;
    L.h[0] = (half_t)(vv.x - (float)H.h[0]);
    L.h[1] = (half_t)(vv.y - (float)H.h[1]);
    L.h[2] = (half_t)(vv.z - (float)H.h[2]);
    L.h[3] = (half_t)(vv.w - (float)H.h[3]);
    *(uint2*)&Xh[(size_t)i * 4] = H.u;
    *(uint2*)&Xl[(size_t)i * 4] = L.u;
  } else if (b < 16384) {
    int j = b - 4096;
    int which = j >> 12, z = (j >> 8) & 15, tb = j & 255;
    int c0 = (tb & 3) * 32, r0 = (tb >> 2) * 32;
    const float* src =
        (which == 0 ? q : which == 1 ? k : v) + (size_t)z * 2048 * 128;
    size_t doff = (size_t)z * 128 * 2048;
    if (which == 0)
      tpose32(src, WTh + doff, WTl + doff, 2048, 128, r0, c0, tile, tid);
    else if (which == 1) {
      size_t koff = (size_t)16 * 128 * 2048 + doff;
      tpose32(src, WTh + koff, WTl + koff, 2048, 128, r0, c0, tile, tid);
    } else
      tpose32(src, VhT + doff, nullptr, 2048, 128, r0, c0, tile, tid);
  } else if (b < 20480) {
    int j = b - 16384;
    int c0 = (j & 63) * 32, r0 = (j >> 6) * 32;
    tpose32(o, OT, nullptr, 2048, 2048, r0, c0, tile, tid);
  } else {
    int idx = (b - 20480) * 256 + tid;  // 0..131071
    int s = idx >> 6, e = idx & 63;
    float th = thetap[0];
    float rate = th * (-(float)e * (1.0f / 64.0f));  // exact e/64
    float rot = (float)s * rate;                     // value numpy takes sin of
    double rev = (double)rot * 0.15915494309189535;  // /(2*pi)
    double fr = rev - rint(rev);
    float thr = (float)(fr * 6.283185307179586);
    float sn = sinf(thr), cs = cosf(thr);
    const float inv4 = 0.2973017787506803f;          // 128^-0.25
    trig[idx] = make_float2(cs * inv4, sn * inv4);
  }
}

// ---------------------------------------------------------------------------
// Split-fp16 projection (3-term) with fused RoPE epilogue.  BM=BN=128, BK=64.
__global__ __launch_bounds__(256, 2)
void k_proj(const half_t* __restrict__ Xh, const half_t* __restrict__ Xl,
            const half_t* __restrict__ WTh, const half_t* __restrict__ WTl,
            const float2* __restrict__ trig, half_t* __restrict__ Rh,
            half_t* __restrict__ Rl) {
  __shared__ __align__(16) char smem[65536];
  half_t* sAh = (half_t*)smem;
  half_t* sAl = (half_t*)(smem + 16384);
  half_t* sBh = (half_t*)(smem + 32768);
  half_t* sBl = (half_t*)(smem + 49152);
  int y = blockIdx.y;
  int m0 = blockIdx.x * 128;
  const half_t* wth = WTh + (size_t)y * 128 * DM;
  const half_t* wtl = WTl + (size_t)y * 128 * DM;
  int lane = threadIdx.x & 63, wave = threadIdx.x >> 6;
  int l15 = lane & 15, quad = lane >> 4;
  int wm = wave >> 1, wn = wave & 1;

  f32x4 acc[4][4];
#pragma unroll
  for (int a = 0; a < 4; ++a)
#pragma unroll
    for (int b = 0; b < 4; ++b) acc[a][b] = (f32x4)0.0f;

  for (int kt = 0; kt < DM / 64; ++kt) {
    int k0 = kt * 64;
#pragma unroll
    for (int i = 0; i < 4; ++i) {
      int c = wave * 4 + i;
      int g = c * 64 + lane;
      int row = g >> 3;
      int lc = (g & 7) ^ (row & 7);
      size_t ro = (size_t)row * DM + k0 + lc * 8;
      gll16(Xh + (size_t)m0 * DM + ro, sAh + c * 512);
      gll16(Xl + (size_t)m0 * DM + ro, sAl + c * 512);
      gll16(wth + ro, sBh + c * 512);
      gll16(wtl + ro, sBl + c * 512);
    }
    __syncthreads();
#pragma unroll
    for (int kk = 0; kk < 2; ++kk) {
      half8 ah[4], al[4], bh[4], bl[4];
#pragma unroll
      for (int t = 0; t < 4; ++t) {
        int ar = wm * 64 + t * 16 + l15;
        int br = wn * 64 + t * 16 + l15;
        int ao = ar * 64 + (((kk * 4 + quad) ^ (ar & 7)) * 8);
        int bo = br * 64 + (((kk * 4 + quad) ^ (br & 7)) * 8);
        ah[t] = *(const half8*)&sAh[ao];
        al[t] = *(const half8*)&sAl[ao];
        bh[t] = *(const half8*)&sBh[bo];
        bl[t] = *(const half8*)&sBl[bo];
      }
#pragma unroll
      for (int im = 0; im < 4; ++im)
#pragma unroll
        for (int in = 0; in < 4; ++in) {
          acc[im][in] = mfma16(ah[im], bh[in], acc[im][in]);
          acc[im][in] = mfma16(ah[im], bl[in], acc[im][in]);
          acc[im][in] = mfma16(al[im], bh[in], acc[im][in]);
        }
    }
    __syncthreads();
  }
  // fused RoPE epilogue
  float* tile = (float*)smem;  // 64 x 132 f32
  size_t ybase = (size_t)y * SEQ * 128;
#pragma unroll
  for (int p = 0; p < 2; ++p) {
    if (p) __syncthreads();
    if (wm == p) {
#pragma unroll
      for (int im = 0; im < 4; ++im)
#pragma unroll
        for (int in = 0; in < 4; ++in)
#pragma unroll
          for (int r = 0; r < 4; ++r)
            tile[(im * 16 + quad * 4 + r) * 132 + wn * 64 + in * 16 + l15] =
                acc[im][in][r];
    }
    __syncthreads();
    int e = lane;
#pragma unroll 4
    for (int rr = 0; rr < 16; ++rr) {
      int rloc = wave * 16 + rr;
      int s = m0 + p * 64 + rloc;
      float x1 = tile[rloc * 132 + e];
      float x2 = tile[rloc * 132 + 64 + e];
      float2 sc = trig[s * 64 + e];
      float y1 = sc.x * x1 - sc.y * x2;
      float y2 = sc.y * x1 + sc.x * x2;
      half_t h1 = (half_t)y1, h2 = (half_t)y2;
      size_t base = ybase + (size_t)s * 128;
      Rh[base + e] = h1;       Rl[base + e] = (half_t)(y1 - (float)h1);
      Rh[base + 64 + e] = h2;  Rl[base + 64 + e] = (half_t)(y2 - (float)h2);
    }
  }
}

// ---------------------------------------------------------------------------
// Single-term fp16 GEMM, BM=64, BN=128, BK=64, 512 blocks = 2/CU.
template <int HALF_OUT>
__global__ __launch_bounds__(256)
void k_gemm1(const half_t* __restrict__ A, const half_t* __restrict__ B,
             void* __restrict__ Cv, float scale) {
  __shared__ __align__(16) half_t sA[64 * 64], sB[128 * 64];
  int am0 = blockIdx.y * 64, bn0 = blockIdx.x * 128;
  int lane = threadIdx.x & 63, wave = threadIdx.x >> 6;
  int l15 = lane & 15, quad = lane >> 4;
  int wm = wave >> 1, wn = wave & 1;

  f32x4 acc[2][4];
#pragma unroll
  for (int a = 0; a < 2; ++a)
#pragma unroll
    for (int b = 0; b < 4; ++b) acc[a][b] = (f32x4)0.0f;

  for (int kt = 0; kt < DM / 64; ++kt) {
    int k0 = kt * 64;
#pragma unroll
    for (int i = 0; i < 2; ++i) {
      int g0 = (i * 4 + wave) * 64;
      int g = g0 + lane;
      int row = g >> 3;
      int lc = (g & 7) ^ (row & 7);
      gll16(A + (size_t)(am0 + row) * 2048 + k0 + lc * 8, sA + g0 * 8);
    }
#pragma unroll
    for (int i = 0; i < 4; ++i) {
      int g0 = (i * 4 + wave) * 64;
      int g = g0 + lane;
      int row = g >> 3;
      int lc = (g & 7) ^ (row & 7);
      gll16(B + (size_t)(bn0 + row) * 2048 + k0 + lc * 8, sB + g0 * 8);
    }
    __syncthreads();
#pragma unroll
    for (int kk = 0; kk < 2; ++kk) {
      half8 ah[2], bh[4];
#pragma unroll
      for (int t = 0; t < 2; ++t) {
        int ar = wm * 32 + t * 16 + l15;
        ah[t] = *(const half8*)&sA[ar * 64 + (((kk * 4 + quad) ^ (ar & 7)) * 8)];
      }
#pragma unroll
      for (int t = 0; t < 4; ++t) {
        int br = wn * 64 + t * 16 + l15;
        bh[t] = *(const half8*)&sB[br * 64 + (((kk * 4 + quad) ^ (br & 7)) * 8)];
      }
#pragma unroll
      for (int im = 0; im < 2; ++im)
#pragma unroll
        for (int in = 0; in < 4; ++in)
          acc[im][in] = mfma16(ah[im], bh[in], acc[im][in]);
    }
    __syncthreads();
  }
#pragma unroll
  for (int im = 0; im < 2; ++im)
#pragma unroll
    for (int in = 0; in < 4; ++in)
#pragma unroll
      for (int r = 0; r < 4; ++r) {
        int row = am0 + wm * 32 + im * 16 + quad * 4 + r;
        int col = bn0 + wn * 64 + in * 16 + l15;
        if (HALF_OUT)
          ((half_t*)Cv)[(size_t)row * 2048 + col] = (half_t)(acc[im][in][r] * scale);
        else
          ((float*)Cv)[(size_t)row * 2048 + col] = acc[im][in][r] * scale;
      }
}

// ---------------------------------------------------------------------------
// Flash attention, causal, split-K.  BM=128 (wave owns 32 q-rows), BN=64.
// Block (h, qt, khalf): khalf 0 does kb in [0,qt], khalf 1 does [qt+1,2qt+1]
// (each qt+1 iters).  512 blocks, complementary pairing -> 17 kb per CU.
// Writes partial m,l and unnormalized fp32 O; k_fmerge combines.
__global__ __launch_bounds__(256, 2)
void k_flash(const half_t* __restrict__ Rh, const half_t* __restrict__ Rl,
             const half_t* __restrict__ VST, float* __restrict__ Op0,
             float* __restrict__ Op1, float* __restrict__ ml) {
  int idx = blockIdx.x;
  int h = idx & 15;
  int khalf = idx < 256 ? 0 : 1;
  int qt = khalf ? ((idx - 256) >> 4) : (15 - (idx >> 4));
  int hq = h * 16 + qt;
  int kb0 = khalf ? (qt + 1) : 0;
  int kb1 = khalf ? (2 * qt + 2) : (qt + 1);
  int lane = threadIdx.x & 63, wave = threadIdx.x >> 6;
  int l15 = lane & 15, quad = lane >> 4;

  const half_t* RQh = Rh + (size_t)h * SEQ * 128;
  const half_t* RQl = Rl + (size_t)h * SEQ * 128;
  const half_t* RKh = Rh + (size_t)(NHEAD + h) * SEQ * 128;
  const half_t* RKl = Rl + (size_t)(NHEAD + h) * SEQ * 128;
  const half_t* Vt  = VST + (size_t)h * 128 * SEQ;  // [v][t]

  __shared__ __align__(16) half_t sKh[64 * 128];
  __shared__ __align__(16) half_t sKl[64 * 128];
  __shared__ __align__(16) half_t sVt[128 * 64];
  __shared__ __align__(16) half_t sP[128 * 72];

  int q0 = qt * 128;

  // Q fragments (hi+lo) for 32 rows, direct from global (L2-resident)
  half8 qh[2][4], ql[2][4];
#pragma unroll
  for (int im = 0; im < 2; ++im)
#pragma unroll
    for (int kk = 0; kk < 4; ++kk) {
      size_t ad =
          (size_t)(q0 + wave * 32 + im * 16 + l15) * 128 + kk * 32 + quad * 8;
      qh[im][kk] = *(const half8*)&RQh[ad];
      ql[im][kk] = *(const half8*)&RQl[ad];
    }

  float m_st[2][4], l_st[2][4];
  f32x4 oacc[2][8];
#pragma unroll
  for (int im = 0; im < 2; ++im)
#pragma unroll
    for (int r = 0; r < 4; ++r) { m_st[im][r] = -INFINITY; l_st[im][r] = 0.0f; }
#pragma unroll
  for (int im = 0; im < 2; ++im)
#pragma unroll
    for (int iv = 0; iv < 8; ++iv) oacc[im][iv] = (f32x4)0.0f;

  for (int kb = kb0; kb < kb1; ++kb) {
    int t0 = kb * 64;
    // ---- stage K (hi+lo, 64x128) and V (128x64), XOR chunk-swizzled ----
#pragma unroll
    for (int i = 0; i < 4; ++i) {
      int c = wave * 4 + i;
      int rk = c * 4 + (lane >> 4);
      int ck = (lane & 15) ^ (rk & 15);
      gll16(RKh + (size_t)(t0 + rk) * 128 + ck * 8, sKh + c * 512);
      gll16(RKl + (size_t)(t0 + rk) * 128 + ck * 8, sKl + c * 512);
      int rv = c * 8 + (lane >> 3);
      int cv = (lane & 7) ^ (rv & 7);
      gll16(Vt + (size_t)rv * SEQ + t0 + cv * 8, sVt + c * 512);
    }
    __syncthreads();

    // wave dead iff all its 32 rows < t0 (t0-q0 is a multiple of 64)
    bool live = (q0 + wave * 32 + 31 >= t0);
    if (live) {
      // ---- S = Q K^T: B-frags read ONCE, feed both im halves (6 MFMA/pair)
      f32x4 sacc[2][4];
#pragma unroll
      for (int im = 0; im < 2; ++im)
#pragma unroll
        for (int in = 0; in < 4; ++in) sacc[im][in] = (f32x4)0.0f;
#pragma unroll
      for (int kk = 0; kk < 4; ++kk)
#pragma unroll
        for (int in = 0; in < 4; ++in) {
          int bo = (in * 16 + l15) * 128 + (((kk * 4 + quad) ^ l15) * 8);
          half8 bh = *(const half8*)&sKh[bo];
          half8 bl = *(const half8*)&sKl[bo];
          sacc[0][in] = mfma16(qh[0][kk], bh, sacc[0][in]);
          sacc[0][in] = mfma16(qh[0][kk], bl, sacc[0][in]);
          sacc[0][in] = mfma16(ql[0][kk], bh, sacc[0][in]);
          sacc[1][in] = mfma16(qh[1][kk], bh, sacc[1][in]);
          sacc[1][in] = mfma16(qh[1][kk], bl, sacc[1][in]);
          sacc[1][in] = mfma16(ql[1][kk], bh, sacc[1][in]);
        }
      if (t0 >= q0) {  // diagonal region: mask t > s (global indices)
#pragma unroll
        for (int im = 0; im < 2; ++im)
#pragma unroll
          for (int in = 0; in < 4; ++in)
#pragma unroll
            for (int r = 0; r < 4; ++r) {
              int sg = q0 + wave * 32 + im * 16 + quad * 4 + r;
              int tg = t0 + in * 16 + l15;
              if (tg > sg) sacc[im][in][r] = -1e30f;
            }
      }
      // ---- online softmax (DPP butterflies), P to LDS, O rescale ----
      float alpha[2][4];
#pragma unroll
      for (int im = 0; im < 2; ++im)
#pragma unroll
        for (int r = 0; r < 4; ++r) {
          float mx = fmaxf(fmaxf(sacc[im][0][r], sacc[im][1][r]),
                           fmaxf(sacc[im][2][r], sacc[im][3][r]));
          mx = red16_max(mx);
          float mnew = fmaxf(m_st[im][r], mx);
          alpha[im][r] = __expf(m_st[im][r] - mnew);
          float sum = 0.0f;
#pragma unroll
          for (int in = 0; in < 4; ++in) {
            float p = __expf(sacc[im][in][r] - mnew);
            sacc[im][in][r] = p;
            sum += p;
          }
          sum = red16_sum(sum);
          l_st[im][r] = l_st[im][r] * alpha[im][r] + sum;
          m_st[im][r] = mnew;
        }
#pragma unroll
      for (int im = 0; im < 2; ++im)
#pragma unroll
        for (int in = 0; in < 4; ++in)
#pragma unroll
          for (int r = 0; r < 4; ++r)
            sP[(wave * 32 + im * 16 + quad * 4 + r) * 72 + in * 16 + l15] =
                (half_t)sacc[im][in][r];
#pragma unroll
      for (int im = 0; im < 2; ++im)
#pragma unroll
        for (int iv = 0; iv < 8; ++iv)
#pragma unroll
          for (int r = 0; r < 4; ++r) oacc[im][iv][r] *= alpha[im][r];

      // ---- O += P @ V (vb read once, feeds both im) ----
#pragma unroll
      for (int kk2 = 0; kk2 < 2; ++kk2) {
        half8 pa0 =
            *(const half8*)&sP[(wave * 32 + l15) * 72 + kk2 * 32 + quad * 8];
        half8 pa1 = *(const half8*)&sP[(wave * 32 + 16 + l15) * 72 +
                                       kk2 * 32 + quad * 8];
#pragma unroll
        for (int iv = 0; iv < 8; ++iv) {
          half8 vb = *(const half8*)&sVt[(iv * 16 + l15) * 64 +
                                         (((kk2 * 4 + quad) ^ (l15 & 7)) * 8)];
          oacc[0][iv] = mfma16(pa0, vb, oacc[0][iv]);
          oacc[1][iv] = mfma16(pa1, vb, oacc[1][iv]);
        }
      }
    }
    __syncthreads();
  }
  // ---- epilogue: partial O (fp32, unnormalized), m, l ----
  float* Ob = (khalf ? Op1 : Op0) + (size_t)hq * 16384;
#pragma unroll
  for (int im = 0; im < 2; ++im)
#pragma unroll
    for (int iv = 0; iv < 8; ++iv)
#pragma unroll
      for (int r = 0; r < 4; ++r) {
        int row = wave * 32 + im * 16 + quad * 4 + r;
        Ob[row * 128 + iv * 16 + l15] = oacc[im][iv][r];
      }
  if (l15 == 0) {
    float* mlw = ml + (size_t)(hq * 2 + khalf) * 256;
#pragma unroll
    for (int im = 0; im < 2; ++im)
#pragma unroll
      for (int r = 0; r < 4; ++r) {
        int row = wave * 32 + im * 16 + quad * 4 + r;
        mlw[row] = m_st[im][r];
        mlw[128 + row] = l_st[im][r];
      }
  }
}

// ---------------------------------------------------------------------------
// Merge the two K-halves: Ybig = (w0*O0 + w1*O1) / (w0*l0 + w1*l1), fp16.
__global__ __launch_bounds__(256)
void k_fmerge(const float* __restrict__ Op0, const float* __restrict__ Op1,
              const float* __restrict__ ml, half_t* __restrict__ Ybig) {
  int hq = blockIdx.x;           // h*16 + qt
  int h = hq >> 4, qt = hq & 15;
  int col = threadIdx.x & 127, rh = threadIdx.x >> 7;
  const float* O0 = Op0 + (size_t)hq * 16384;
  const float* O1 = Op1 + (size_t)hq * 16384;
  const float* mlb = ml + (size_t)hq * 512;
  for (int r = rh * 64; r < rh * 64 + 64; ++r) {
    float m0 = mlb[r], l0 = mlb[128 + r];
    float m1 = mlb[256 + r], l1 = mlb[384 + r];
    float mm = fmaxf(m0, m1);
    float w0 = __expf(m0 - mm), w1 = __expf(m1 - mm);
    float den = w0 * l0 + w1 * l1;
    float val = (w0 * O0[r * 128 + col] + w1 * O1[r * 128 + col]) / den;
    Ybig[(size_t)(qt * 128 + r) * 2048 + h * 128 + col] = (half_t)val;
  }
}

// ---------------------------------------------------------------------------
extern "C" void kernel_launch(void* const* d_in, const int* in_sizes, int n_in,
                              void* d_out, int out_size, void* d_ws,
                              size_t ws_size, hipStream_t stream) {
  const float* x = (const float*)d_in[0];
  const float* q = (const float*)d_in[1];
  const float* k = (const float*)d_in[2];
  const float* v = (const float*)d_in[3];
  const float* o = (const float*)d_in[4];
  const float* theta = (const float*)d_in[5];
  float* out = (float*)d_out;

  char* ws = (char*)d_ws;
  const size_t HB = (size_t)2048 * 2048 * 2;  // 8 MiB
  half_t* Xh   = (half_t*)(ws);            // [2048 s][2048 d]   dead after v-proj
  half_t* Xl   = (half_t*)(ws + HB);       //                    dead after proj
  half_t* WTh  = (half_t*)(ws + 2 * HB);   // [2][16][128][2048] dead after proj
  half_t* WTl  = (half_t*)(ws + 4 * HB);   //                    dead after proj
  half_t* VhT  = (half_t*)(ws + 6 * HB);   // [16][128][2048]    dead after v-proj
  half_t* OT   = (half_t*)(ws + 7 * HB);   // [2048 d][2048 hv]  live to the end
  half_t* Rh   = (half_t*)(ws + 8 * HB);   // [2][16][2048][128]
  half_t* Rl   = (half_t*)(ws + 10 * HB);
  float2* trig = (float2*)(ws + 12 * HB);  // 1 MB
  half_t* VST  = (half_t*)(ws + 2 * HB);   // overlay WTh lower (live in flash)
  half_t* Ybig = (half_t*)(ws + 3 * HB);   // overlay WTh upper
  float*  Op0  = (float*)(ws);             // 16 MB overlay Xh/Xl (dead)
  float*  Op1  = (float*)(ws + 4 * HB);    // 16 MB overlay WTl (dead)
  float*  mlb  = (float*)(ws + 6 * HB);    // 512 KB overlay VhT (dead)

  // 1. preprocessing: split, 4 transposes, trig table (one launch)
  k_pre<<<20992, 256, 0, stream>>>(x, q, k, v, o, theta, Xh, Xl, WTh, WTl,
                                   VhT, OT, trig);
  // 2. q/k projections + fused rope -> Rh/Rl
  k_proj<<<dim3(16, 32), 256, 0, stream>>>(Xh, Xl, WTh, WTl, trig, Rh, Rl);
  // 3. v projection -> VS^T [h][v][t] fp16
  k_gemm1<1><<<dim3(16, 32), 256, 0, stream>>>(VhT, Xh, VST, 1.0f);
  // 4. flash attention (split-K partials)
  k_flash<<<512, 256, 0, stream>>>(Rh, Rl, VST, Op0, Op1, mlb);
  // 5. merge partials -> Ybig [s][h*128+v] fp16
  k_fmerge<<<256, 256, 0, stream>>>(Op0, Op1, mlb, Ybig);
  // 6. out projection: z = Ybig @ OT * (1/2048) -> fp32
  k_gemm1<0><<<dim3(16, 32), 256, 0, stream>>>(Ybig, OT, out, 1.0f / 2048.0f);
}

// Round 7
// 336.189 us; speedup vs baseline: 1.0962x; 1.0962x over previous
//
#include <hip/hip_runtime.h>
#include <math.h>

// ---------------------------------------------------------------------------
// ShrdMHAttention: z = (sum_h softmax_causal(rope(xQ) rope(xK)^T) (xV) O_h) * scale
// SEQ=2048, D_MODEL=2048, NH=16, DQK=DV=128.
//
// Precision: q/k proj and QK^T use 2-term fp16 split (hh+hl+lh); v/PV/out are
// single fp16.  Measured absmax 0.031 vs 0.102 threshold (R1-R6).
//
// R7: revert flash to R5 design (R6 split-K regressed: partial-write +
// merge overhead ate the LDS saving).  gemm1 gets an XCD-compact 2D block
// swizzle (each XCD owns 4 bn x 16 am tiles -> HBM fetch ~393->~48 MB).
// ---------------------------------------------------------------------------

typedef _Float16 half_t;
typedef __attribute__((ext_vector_type(8))) _Float16 half8;
typedef __attribute__((ext_vector_type(4))) float f32x4;

#define SEQ   2048
#define DM    2048
#define NHEAD 16

__device__ __forceinline__ f32x4 mfma16(half8 a, half8 b, f32x4 c) {
  return __builtin_amdgcn_mfma_f32_16x16x32_f16(a, b, c, 0, 0, 0);
}

__device__ __forceinline__ void gll16(const half_t* g, half_t* l) {
  __builtin_amdgcn_global_load_lds(
      (const __attribute__((address_space(1))) unsigned int*)g,
      (__attribute__((address_space(3))) unsigned int*)l, 16, 0, 0);
}

// DPP lane-permute within contiguous 16-lane rows (VALU, no LDS pipe).
template <int CTRL>
__device__ __forceinline__ float dppf(float v) {
  int r = __builtin_amdgcn_mov_dpp(__builtin_bit_cast(int, v), CTRL, 0xF, 0xF,
                                   true);
  return __builtin_bit_cast(float, r);
}
__device__ __forceinline__ float red16_max(float v) {
  v = fmaxf(v, dppf<0xB1>(v));   // quad_perm [1,0,3,2]
  v = fmaxf(v, dppf<0x4E>(v));   // quad_perm [2,3,0,1]
  v = fmaxf(v, dppf<0x141>(v));  // row_half_mirror
  v = fmaxf(v, dppf<0x140>(v));  // row_mirror
  return v;
}
__device__ __forceinline__ float red16_sum(float v) {
  v += dppf<0xB1>(v);
  v += dppf<0x4E>(v);
  v += dppf<0x141>(v);
  v += dppf<0x140>(v);
  return v;
}

// ---------------------------------------------------------------------------
// k_pre: one launch for x hi/lo split, q/k/v/o transposes, trig table.
__device__ __forceinline__ void tpose32(const float* __restrict__ in,
                                        half_t* __restrict__ hi,
                                        half_t* __restrict__ lo, int R, int C,
                                        int r0, int c0, float (*tile)[33],
                                        int tid) {
  int tx = tid & 31, ty = tid >> 5;
#pragma unroll
  for (int i = 0; i < 32; i += 8)
    tile[ty + i][tx] = in[(size_t)(r0 + ty + i) * C + c0 + tx];
  __syncthreads();
#pragma unroll
  for (int i = 0; i < 32; i += 8) {
    float v = tile[tx][ty + i];
    half_t h = (half_t)v;
    size_t oidx = (size_t)(c0 + ty + i) * R + r0 + tx;
    hi[oidx] = h;
    if (lo) lo[oidx] = (half_t)(v - (float)h);
  }
}

__global__ __launch_bounds__(256)
void k_pre(const float* __restrict__ x, const float* __restrict__ q,
           const float* __restrict__ k, const float* __restrict__ v,
           const float* __restrict__ o, const float* __restrict__ thetap,
           half_t* __restrict__ Xh, half_t* __restrict__ Xl,
           half_t* __restrict__ WTh, half_t* __restrict__ WTl,
           half_t* __restrict__ VhT, half_t* __restrict__ OT,
           float2* __restrict__ trig) {
  __shared__ float tile[32][33];
  int b = blockIdx.x, tid = threadIdx.x;
  if (b < 4096) {
    int i = b * 256 + tid;
    float4 vv = ((const float4*)x)[i];
    union { half_t h[4]; uint2 u; } H, L;
    H.h[0] = (half_t)vv.x; H.h[1] = (half_t)vv.y;
    H.h[2] = (half_t)vv.z; H.h[3] = (half_t)vv.w;
    L.h[0] = (half_t)(vv.x - (float)H.h[0]);
    L.h[1] = (half_t)(vv.y - (float)H.h[1]);
    L.h[2] = (half_t)(vv.z - (float)H.h[2]);
    L.h[3] = (half_t)(vv.w - (float)H.h[3]);
    *(uint2*)&Xh[(size_t)i * 4] = H.u;
    *(uint2*)&Xl[(size_t)i * 4] = L.u;
  } else if (b < 16384) {
    int j = b - 4096;
    int which = j >> 12, z = (j >> 8) & 15, tb = j & 255;
    int c0 = (tb & 3) * 32, r0 = (tb >> 2) * 32;
    const float* src =
        (which == 0 ? q : which == 1 ? k : v) + (size_t)z * 2048 * 128;
    size_t doff = (size_t)z * 128 * 2048;
    if (which == 0)
      tpose32(src, WTh + doff, WTl + doff, 2048, 128, r0, c0, tile, tid);
    else if (which == 1) {
      size_t koff = (size_t)16 * 128 * 2048 + doff;
      tpose32(src, WTh + koff, WTl + koff, 2048, 128, r0, c0, tile, tid);
    } else
      tpose32(src, VhT + doff, nullptr, 2048, 128, r0, c0, tile, tid);
  } else if (b < 20480) {
    int j = b - 16384;
    int c0 = (j & 63) * 32, r0 = (j >> 6) * 32;
    tpose32(o, OT, nullptr, 2048, 2048, r0, c0, tile, tid);
  } else {
    int idx = (b - 20480) * 256 + tid;  // 0..131071
    int s = idx >> 6, e = idx & 63;
    float th = thetap[0];
    float rate = th * (-(float)e * (1.0f / 64.0f));  // exact e/64
    float rot = (float)s * rate;                     // value numpy takes sin of
    double rev = (double)rot * 0.15915494309189535;  // /(2*pi)
    double fr = rev - rint(rev);
    float thr = (float)(fr * 6.283185307179586);
    float sn = sinf(thr), cs = cosf(thr);
    const float inv4 = 0.2973017787506803f;          // 128^-0.25
    trig[idx] = make_float2(cs * inv4, sn * inv4);
  }
}

// ---------------------------------------------------------------------------
// Split-fp16 projection (3-term) with fused RoPE epilogue.  BM=BN=128, BK=64.
__global__ __launch_bounds__(256, 2)
void k_proj(const half_t* __restrict__ Xh, const half_t* __restrict__ Xl,
            const half_t* __restrict__ WTh, const half_t* __restrict__ WTl,
            const float2* __restrict__ trig, half_t* __restrict__ Rh,
            half_t* __restrict__ Rl) {
  __shared__ __align__(16) char smem[65536];
  half_t* sAh = (half_t*)smem;
  half_t* sAl = (half_t*)(smem + 16384);
  half_t* sBh = (half_t*)(smem + 32768);
  half_t* sBl = (half_t*)(smem + 49152);
  int y = blockIdx.y;
  int m0 = blockIdx.x * 128;
  const half_t* wth = WTh + (size_t)y * 128 * DM;
  const half_t* wtl = WTl + (size_t)y * 128 * DM;
  int lane = threadIdx.x & 63, wave = threadIdx.x >> 6;
  int l15 = lane & 15, quad = lane >> 4;
  int wm = wave >> 1, wn = wave & 1;

  f32x4 acc[4][4];
#pragma unroll
  for (int a = 0; a < 4; ++a)
#pragma unroll
    for (int b = 0; b < 4; ++b) acc[a][b] = (f32x4)0.0f;

  for (int kt = 0; kt < DM / 64; ++kt) {
    int k0 = kt * 64;
#pragma unroll
    for (int i = 0; i < 4; ++i) {
      int c = wave * 4 + i;
      int g = c * 64 + lane;
      int row = g >> 3;
      int lc = (g & 7) ^ (row & 7);
      size_t ro = (size_t)row * DM + k0 + lc * 8;
      gll16(Xh + (size_t)m0 * DM + ro, sAh + c * 512);
      gll16(Xl + (size_t)m0 * DM + ro, sAl + c * 512);
      gll16(wth + ro, sBh + c * 512);
      gll16(wtl + ro, sBl + c * 512);
    }
    __syncthreads();
#pragma unroll
    for (int kk = 0; kk < 2; ++kk) {
      half8 ah[4], al[4], bh[4], bl[4];
#pragma unroll
      for (int t = 0; t < 4; ++t) {
        int ar = wm * 64 + t * 16 + l15;
        int br = wn * 64 + t * 16 + l15;
        int ao = ar * 64 + (((kk * 4 + quad) ^ (ar & 7)) * 8);
        int bo = br * 64 + (((kk * 4 + quad) ^ (br & 7)) * 8);
        ah[t] = *(const half8*)&sAh[ao];
        al[t] = *(const half8*)&sAl[ao];
        bh[t] = *(const half8*)&sBh[bo];
        bl[t] = *(const half8*)&sBl[bo];
      }
#pragma unroll
      for (int im = 0; im < 4; ++im)
#pragma unroll
        for (int in = 0; in < 4; ++in) {
          acc[im][in] = mfma16(ah[im], bh[in], acc[im][in]);
          acc[im][in] = mfma16(ah[im], bl[in], acc[im][in]);
          acc[im][in] = mfma16(al[im], bh[in], acc[im][in]);
        }
    }
    __syncthreads();
  }
  // fused RoPE epilogue
  float* tile = (float*)smem;  // 64 x 132 f32
  size_t ybase = (size_t)y * SEQ * 128;
#pragma unroll
  for (int p = 0; p < 2; ++p) {
    if (p) __syncthreads();
    if (wm == p) {
#pragma unroll
      for (int im = 0; im < 4; ++im)
#pragma unroll
        for (int in = 0; in < 4; ++in)
#pragma unroll
          for (int r = 0; r < 4; ++r)
            tile[(im * 16 + quad * 4 + r) * 132 + wn * 64 + in * 16 + l15] =
                acc[im][in][r];
    }
    __syncthreads();
    int e = lane;
#pragma unroll 4
    for (int rr = 0; rr < 16; ++rr) {
      int rloc = wave * 16 + rr;
      int s = m0 + p * 64 + rloc;
      float x1 = tile[rloc * 132 + e];
      float x2 = tile[rloc * 132 + 64 + e];
      float2 sc = trig[s * 64 + e];
      float y1 = sc.x * x1 - sc.y * x2;
      float y2 = sc.y * x1 + sc.x * x2;
      half_t h1 = (half_t)y1, h2 = (half_t)y2;
      size_t base = ybase + (size_t)s * 128;
      Rh[base + e] = h1;       Rl[base + e] = (half_t)(y1 - (float)h1);
      Rh[base + 64 + e] = h2;  Rl[base + 64 + e] = (half_t)(y2 - (float)h2);
    }
  }
}

// ---------------------------------------------------------------------------
// Single-term fp16 GEMM, BM=64, BN=128, BK=64, 512 blocks = 2/CU.
// XCD-compact swizzle: XCD x owns bn in [ (x&3)*4, +4 ), am in [ (x>>2)*16, +16 )
// -> per-XCD fetch = 4 B-strips + 16 A-strips = 6 MB (was: full A per XCD).
template <int HALF_OUT>
__global__ __launch_bounds__(256)
void k_gemm1(const half_t* __restrict__ A, const half_t* __restrict__ B,
             void* __restrict__ Cv, float scale) {
  __shared__ __align__(16) half_t sA[64 * 64], sB[128 * 64];
  int lin = blockIdx.y * 16 + blockIdx.x;
  int xcd = lin & 7, slot = lin >> 3;          // 8 XCDs x 64 slots
  int bx = (xcd & 3) * 4 + (slot & 3);         // 16 bn tiles
  int by = (xcd >> 2) * 16 + (slot >> 2);      // 32 am tiles
  int am0 = by * 64, bn0 = bx * 128;
  int lane = threadIdx.x & 63, wave = threadIdx.x >> 6;
  int l15 = lane & 15, quad = lane >> 4;
  int wm = wave >> 1, wn = wave & 1;

  f32x4 acc[2][4];
#pragma unroll
  for (int a = 0; a < 2; ++a)
#pragma unroll
    for (int b = 0; b < 4; ++b) acc[a][b] = (f32x4)0.0f;

  for (int kt = 0; kt < DM / 64; ++kt) {
    int k0 = kt * 64;
#pragma unroll
    for (int i = 0; i < 2; ++i) {
      int g0 = (i * 4 + wave) * 64;
      int g = g0 + lane;
      int row = g >> 3;
      int lc = (g & 7) ^ (row & 7);
      gll16(A + (size_t)(am0 + row) * 2048 + k0 + lc * 8, sA + g0 * 8);
    }
#pragma unroll
    for (int i = 0; i < 4; ++i) {
      int g0 = (i * 4 + wave) * 64;
      int g = g0 + lane;
      int row = g >> 3;
      int lc = (g & 7) ^ (row & 7);
      gll16(B + (size_t)(bn0 + row) * 2048 + k0 + lc * 8, sB + g0 * 8);
    }
    __syncthreads();
#pragma unroll
    for (int kk = 0; kk < 2; ++kk) {
      half8 ah[2], bh[4];
#pragma unroll
      for (int t = 0; t < 2; ++t) {
        int ar = wm * 32 + t * 16 + l15;
        ah[t] = *(const half8*)&sA[ar * 64 + (((kk * 4 + quad) ^ (ar & 7)) * 8)];
      }
#pragma unroll
      for (int t = 0; t < 4; ++t) {
        int br = wn * 64 + t * 16 + l15;
        bh[t] = *(const half8*)&sB[br * 64 + (((kk * 4 + quad) ^ (br & 7)) * 8)];
      }
#pragma unroll
      for (int im = 0; im < 2; ++im)
#pragma unroll
        for (int in = 0; in < 4; ++in)
          acc[im][in] = mfma16(ah[im], bh[in], acc[im][in]);
    }
    __syncthreads();
  }
#pragma unroll
  for (int im = 0; im < 2; ++im)
#pragma unroll
    for (int in = 0; in < 4; ++in)
#pragma unroll
      for (int r = 0; r < 4; ++r) {
        int row = am0 + wm * 32 + im * 16 + quad * 4 + r;
        int col = bn0 + wn * 64 + in * 16 + l15;
        if (HALF_OUT)
          ((half_t*)Cv)[(size_t)row * 2048 + col] = (half_t)(acc[im][in][r] * scale);
        else
          ((float*)Cv)[(size_t)row * 2048 + col] = acc[im][in][r] * scale;
      }
}

// ---------------------------------------------------------------------------
// Flash attention, causal (R5 design).  BM=BN=64, wave owns 16 q-rows.
// Grid 512 = 32 qtiles x 16 heads, complementary qt pairing (uniform 33
// k-iters per CU).  2 blocks/CU.  DPP softmax reductions.
__global__ __launch_bounds__(256, 2)
void k_flash(const half_t* __restrict__ Rh, const half_t* __restrict__ Rl,
             const half_t* __restrict__ VST, half_t* __restrict__ Ybig) {
  int idx = blockIdx.x;
  int h = idx & 15;
  int qt = (idx < 256) ? (31 - (idx >> 4)) : ((idx - 256) >> 4);
  int lane = threadIdx.x & 63, wave = threadIdx.x >> 6;
  int l15 = lane & 15, quad = lane >> 4;

  const half_t* RQh = Rh + (size_t)h * SEQ * 128;
  const half_t* RQl = Rl + (size_t)h * SEQ * 128;
  const half_t* RKh = Rh + (size_t)(NHEAD + h) * SEQ * 128;
  const half_t* RKl = Rl + (size_t)(NHEAD + h) * SEQ * 128;
  const half_t* Vt  = VST + (size_t)h * 128 * SEQ;  // [v][t]

  __shared__ __align__(16) half_t sKh[64 * 128];
  __shared__ __align__(16) half_t sKl[64 * 128];
  __shared__ __align__(16) half_t sVt[128 * 64];
  __shared__ __align__(16) half_t sP[64 * 72];

  int q0 = qt * 64;

  half8 qh[4], ql[4];
#pragma unroll
  for (int kk = 0; kk < 4; ++kk) {
    size_t ad = (size_t)(q0 + wave * 16 + l15) * 128 + kk * 32 + quad * 8;
    qh[kk] = *(const half8*)&RQh[ad];
    ql[kk] = *(const half8*)&RQl[ad];
  }

  float m_st[4], l_st[4];
  f32x4 oacc[8];
#pragma unroll
  for (int r = 0; r < 4; ++r) { m_st[r] = -INFINITY; l_st[r] = 0.0f; }
#pragma unroll
  for (int iv = 0; iv < 8; ++iv) oacc[iv] = (f32x4)0.0f;

  int nkb = qt + 1;
  for (int kb = 0; kb < nkb; ++kb) {
    int t0 = kb * 64;
#pragma unroll
    for (int i = 0; i < 4; ++i) {
      int c = wave * 4 + i;
      int rk = c * 4 + (lane >> 4);       // K row 0..63 (16 chunks/row)
      int ck = (lane & 15) ^ (rk & 15);
      gll16(RKh + (size_t)(t0 + rk) * 128 + ck * 8, sKh + c * 512);
      gll16(RKl + (size_t)(t0 + rk) * 128 + ck * 8, sKl + c * 512);
      int rv = c * 8 + (lane >> 3);       // V row 0..127 (8 chunks/row)
      int cv = (lane & 7) ^ (rv & 7);
      gll16(Vt + (size_t)rv * SEQ + t0 + cv * 8, sVt + c * 512);
    }
    __syncthreads();

    f32x4 sacc[4];
#pragma unroll
    for (int in = 0; in < 4; ++in) sacc[in] = (f32x4)0.0f;
#pragma unroll
    for (int kk = 0; kk < 4; ++kk)
#pragma unroll
      for (int in = 0; in < 4; ++in) {
        int bo = (in * 16 + l15) * 128 + (((kk * 4 + quad) ^ l15) * 8);
        half8 bh = *(const half8*)&sKh[bo];
        half8 bl = *(const half8*)&sKl[bo];
        sacc[in] = mfma16(qh[kk], bh, sacc[in]);
        sacc[in] = mfma16(qh[kk], bl, sacc[in]);
        sacc[in] = mfma16(ql[kk], bh, sacc[in]);
      }
    if (kb == qt) {  // diagonal block: mask t > s (local indices)
#pragma unroll
      for (int in = 0; in < 4; ++in)
#pragma unroll
        for (int r = 0; r < 4; ++r)
          if (in * 16 + l15 > wave * 16 + quad * 4 + r) sacc[in][r] = -1e30f;
    }
    float alpha[4];
#pragma unroll
    for (int r = 0; r < 4; ++r) {
      float mx = fmaxf(fmaxf(sacc[0][r], sacc[1][r]),
                       fmaxf(sacc[2][r], sacc[3][r]));
      mx = red16_max(mx);
      float mnew = fmaxf(m_st[r], mx);
      alpha[r] = __expf(m_st[r] - mnew);
      float sum = 0.0f;
#pragma unroll
      for (int in = 0; in < 4; ++in) {
        float p = __expf(sacc[in][r] - mnew);
        sacc[in][r] = p;
        sum += p;
      }
      sum = red16_sum(sum);
      l_st[r] = l_st[r] * alpha[r] + sum;
      m_st[r] = mnew;
    }
#pragma unroll
    for (int in = 0; in < 4; ++in)
#pragma unroll
      for (int r = 0; r < 4; ++r)
        sP[(wave * 16 + quad * 4 + r) * 72 + in * 16 + l15] =
            (half_t)sacc[in][r];
#pragma unroll
    for (int iv = 0; iv < 8; ++iv)
#pragma unroll
      for (int r = 0; r < 4; ++r) oacc[iv][r] *= alpha[r];

#pragma unroll
    for (int kk2 = 0; kk2 < 2; ++kk2) {
      half8 pa =
          *(const half8*)&sP[(wave * 16 + l15) * 72 + kk2 * 32 + quad * 8];
#pragma unroll
      for (int iv = 0; iv < 8; ++iv) {
        half8 vb = *(const half8*)&sVt[(iv * 16 + l15) * 64 +
                                       (((kk2 * 4 + quad) ^ (l15 & 7)) * 8)];
        oacc[iv] = mfma16(pa, vb, oacc[iv]);
      }
    }
    __syncthreads();
  }
  float invl[4];
#pragma unroll
  for (int r = 0; r < 4; ++r) invl[r] = 1.0f / l_st[r];
#pragma unroll
  for (int iv = 0; iv < 8; ++iv)
#pragma unroll
    for (int r = 0; r < 4; ++r) {
      int row = q0 + wave * 16 + quad * 4 + r;
      int col = h * 128 + iv * 16 + l15;
      Ybig[(size_t)row * 2048 + col] = (half_t)(oacc[iv][r] * invl[r]);
    }
}

// ---------------------------------------------------------------------------
extern "C" void kernel_launch(void* const* d_in, const int* in_sizes, int n_in,
                              void* d_out, int out_size, void* d_ws,
                              size_t ws_size, hipStream_t stream) {
  const float* x = (const float*)d_in[0];
  const float* q = (const float*)d_in[1];
  const float* k = (const float*)d_in[2];
  const float* v = (const float*)d_in[3];
  const float* o = (const float*)d_in[4];
  const float* theta = (const float*)d_in[5];
  float* out = (float*)d_out;

  char* ws = (char*)d_ws;
  const size_t HB = (size_t)2048 * 2048 * 2;  // 8 MiB
  half_t* Xh   = (half_t*)(ws);            // [2048 s][2048 d]
  half_t* Xl   = (half_t*)(ws + HB);
  half_t* WTh  = (half_t*)(ws + 2 * HB);   // [2][16][128 e][2048 d] (2 HB)
  half_t* WTl  = (half_t*)(ws + 4 * HB);   // (2 HB)
  half_t* VhT  = (half_t*)(ws + 6 * HB);   // [16][128 v][2048 d]
  half_t* OT   = (half_t*)(ws + 7 * HB);   // [2048 d][2048 hv]
  half_t* Rh   = (half_t*)(ws + 8 * HB);   // [2][16][2048 s][128 e] (2 HB)
  half_t* Rl   = (half_t*)(ws + 10 * HB);  // (2 HB)
  float2* trig = (float2*)(ws + 12 * HB);  // 1 MB
  half_t* VST  = (half_t*)(ws + 2 * HB);   // overlay WTh (dead after proj)
  half_t* Ybig = (half_t*)(ws + 3 * HB);   // overlay WTh upper half

  // 1. preprocessing: split, 4 transposes, trig table (one launch)
  k_pre<<<20992, 256, 0, stream>>>(x, q, k, v, o, theta, Xh, Xl, WTh, WTl,
                                   VhT, OT, trig);
  // 2. q/k projections + fused rope -> Rh/Rl
  k_proj<<<dim3(16, 32), 256, 0, stream>>>(Xh, Xl, WTh, WTl, trig, Rh, Rl);
  // 3. v projection -> VS^T [h][v][t] fp16
  k_gemm1<1><<<dim3(16, 32), 256, 0, stream>>>(VhT, Xh, VST, 1.0f);
  // 4. flash attention -> Ybig [s][h*128+v] fp16
  k_flash<<<512, 256, 0, stream>>>(Rh, Rl, VST, Ybig);
  // 5. out projection: z = Ybig @ OT * (1/2048) -> fp32
  k_gemm1<0><<<dim3(16, 32), 256, 0, stream>>>(Ybig, OT, out, 1.0f / 2048.0f);
}